// Round 5
// baseline (214.742 us; speedup 1.0000x reference)
//
#include <hip/hip_runtime.h>

#define N_NODES 50000
#define N_EDGES 800000
#define D 128
#define NB 782            // ceil(50000/64) buckets of 64 nodes
#define SORT_CAP 2048

typedef __attribute__((ext_vector_type(8))) short bf16x8;   // MFMA A/B frag
typedef __attribute__((ext_vector_type(4))) float floatx4;  // MFMA C/D frag

__device__ __forceinline__ unsigned short f2bf(float f) {
  unsigned u = __builtin_bit_cast(unsigned, f);
  unsigned r = u + 0x7FFFu + ((u >> 16) & 1u);  // RNE
  return (unsigned short)(r >> 16);
}
__device__ __forceinline__ float bf2f_lo(unsigned u) {
  return __builtin_bit_cast(float, u << 16);
}
__device__ __forceinline__ float bf2f_hi(unsigned u) {
  return __builtin_bit_cast(float, u & 0xFFFF0000u);
}
__device__ __forceinline__ uint2 pack4bf(float4 v) {
  unsigned a = f2bf(v.x), b = f2bf(v.y), c = f2bf(v.z), d = f2bf(v.w);
  return uint2{a | (b << 16), c | (d << 16)};
}

// ===========================================================================
// wconv: one-shot W f32 -> bf16 (32 KB), L1-resident for all gemm tiles.
// ===========================================================================
__global__ __launch_bounds__(256) void wconv_kernel(
    const float* __restrict__ W, unsigned short* __restrict__ wbf) {
  int i = blockIdx.x * 256 + threadIdx.x;   // 16 blocks * 256t * 4 = 16384
  float4 v = *(const float4*)(W + (size_t)i * 4);
  *(uint2*)(wbf + (size_t)i * 4) = pack4bf(v);
}

// ===========================================================================
// prep_kernel: fused [bin blocks | gemm tiles] in one grid.
// R13: BIN_CHUNK 4096 -> 2048 (391 bin blocks).  prep was stuck at ~40us
// across R10-R12 because bin blocks are ~1/CU and their SERIAL critical path
// (hist atomics + scan + scatter) IS prep's duration; halving the chunk
// halves that path.  LDS union ~17.6 KB.
// ===========================================================================
#define LDA 136
#define BIN_T 256
#define BIN_CHUNK 2048
#define BIN_BLOCKS 391   // 391*2048 = 800768 >= 800000 (last block partial)
#define OFFS_W 783       // 782 bucket starts + total

struct BinShm {
  unsigned stage[BIN_CHUNK];   // 8 KB
  int hcnt[NB];
  int hstart[NB];
  int hcur[NB];
  int wsums[4];
  int tot;
};
struct GemmShm {
  unsigned short As[64 * LDA];    // 17.4 KB
};
union PrepShm {
  BinShm bin;
  GemmShm gemm;
};

__global__ __launch_bounds__(256) void prep_kernel(
    const float* __restrict__ x, const unsigned short* __restrict__ wbf,
    unsigned short* __restrict__ y,
    const int* __restrict__ src, const int* __restrict__ dst,
    unsigned* __restrict__ ebuf, int* __restrict__ offs) {
  __shared__ PrepShm shm;
  int t = threadIdx.x;

  if (blockIdx.x >= BIN_BLOCKS) {
    // ---------------- GEMM tile: y[row0..row0+64) = bf16(x @ W^T) ----------
    unsigned short* As = shm.gemm.As;
    int row0 = (blockIdx.x - BIN_BLOCKS) * 64;

    for (int i = t; i < 2048; i += 256) {
      int r = i >> 5;
      int c4 = (i & 31) * 4;
      int gr = row0 + r;
      float4 v = (gr < N_NODES) ? *(const float4*)(x + (size_t)gr * D + c4)
                                : float4{0.f, 0.f, 0.f, 0.f};
      *(uint2*)&As[r * LDA + c4] = pack4bf(v);
    }
    __syncthreads();

    int w = t >> 6;
    int lane = t & 63;
    int ln = lane & 15;
    int quad = lane >> 4;

    floatx4 acc[8];
#pragma unroll
    for (int n = 0; n < 8; ++n) acc[n] = floatx4{0.f, 0.f, 0.f, 0.f};

#pragma unroll
    for (int ks = 0; ks < 4; ++ks) {
      int kc = ks * 32 + quad * 8;
      bf16x8 a = *(const bf16x8*)&As[(w * 16 + ln) * LDA + kc];
#pragma unroll
      for (int n = 0; n < 8; ++n) {
        bf16x8 bf = *(const bf16x8*)&wbf[(size_t)(n * 16 + ln) * D + kc];
        acc[n] = __builtin_amdgcn_mfma_f32_16x16x32_bf16(a, bf, acc[n], 0, 0, 0);
      }
    }

    // D layout: col = lane&15, row = quad*4 + reg.
    int gr0 = row0 + w * 16 + quad * 4;
#pragma unroll
    for (int n = 0; n < 8; ++n) {
      int gc = n * 16 + ln;
#pragma unroll
      for (int r = 0; r < 4; ++r) {
        int gr = gr0 + r;
        if (gr < N_NODES) y[(size_t)gr * D + gc] = f2bf(acc[n][r]);
      }
    }
  } else {
    // ---------------- bin block: bucket-group 2048 edges, own segment ------
    BinShm& B = shm.bin;
    int blk = blockIdx.x;
    int e0 = blk * BIN_CHUNK;
    for (int i = t; i < NB; i += BIN_T) B.hcnt[i] = 0;
    __syncthreads();

    unsigned pk[8];
    short bk[8];
#pragma unroll
    for (int j = 0; j < 8; ++j) {
      int e = e0 + j * BIN_T + t;
      bk[j] = -1;
      if (e < N_EDGES) {
        int d = dst[e];
        int s = src[e];
        pk[j] = ((unsigned)s << 6) | (unsigned)(d & 63);
        bk[j] = (short)(d >> 6);
        atomicAdd(&B.hcnt[d >> 6], 1);
      }
    }
    __syncthreads();

    // exclusive scan of hcnt[782]: 4 counters/thread (256*4=1024 >= 782)
    int c4[4];
    int s4 = 0;
    int base4 = t * 4;
#pragma unroll
    for (int j = 0; j < 4; ++j) {
      int idx = base4 + j;
      c4[j] = (idx < NB) ? B.hcnt[idx] : 0;
      s4 += c4[j];
    }
    int incl = s4;
    int lane = t & 63, wid = t >> 6;
#pragma unroll
    for (int off = 1; off < 64; off <<= 1) {
      int n = __shfl_up(incl, off);
      if (lane >= off) incl += n;
    }
    if (lane == 63) B.wsums[wid] = incl;
    __syncthreads();
    int wbase = 0;
    for (int w2 = 0; w2 < wid; ++w2) wbase += B.wsums[w2];
    int run = wbase + incl - s4;
#pragma unroll
    for (int j = 0; j < 4; ++j) {
      int idx = base4 + j;
      if (idx < NB) { B.hstart[idx] = run; B.hcur[idx] = run; }
      run += c4[j];
    }
    if (t == BIN_T - 1) B.tot = run;
    __syncthreads();

    // scatter into stage grouped by bucket (scalar LDS atomics only)
#pragma unroll
    for (int j = 0; j < 8; ++j) {
      if (bk[j] >= 0) {
        int p = atomicAdd(&B.hcur[bk[j]], 1);
        B.stage[p] = pk[j];
      }
    }
    __syncthreads();

    // flush: fully coalesced copy of this block's segment (uint4 wide)
    int tot = B.tot;
    unsigned* dseg = ebuf + (size_t)blk * BIN_CHUNK;
    int tot4 = tot >> 2;
    uint4* d4 = (uint4*)dseg;
    const uint4* s4p = (const uint4*)B.stage;
    for (int i = t; i < tot4; i += BIN_T) d4[i] = s4p[i];
    for (int i = (tot & ~3) + t; i < tot; i += BIN_T) dseg[i] = B.stage[i];

    // publish per-bucket offsets (coalesced, no atomics)
    int* orow = offs + (size_t)blk * OFFS_W;
    for (int i = t; i < NB; i += BIN_T) orow[i] = B.hstart[i];
    if (t == 0) orow[NB] = tot;
  }
}

// ===========================================================================
// gather_sorted: block per bucket, 256t.  R13: COLUMN-QUARTER passes --
// q=0..3 over 32-col slices; per pass each 4-lane group reads 64B of one
// y-row (16 edges in flight/wave).  Per-pass y slice = 3.2 MB -> fits the
// 4 MiB per-XCD L2 (R12 counters: FETCH 87 MB vs 16.6 MB unique => the full
// 256B-row pattern thrashed L2/L3 to HBM).
// ===========================================================================
__global__ __launch_bounds__(256) void gather_sorted(
    const unsigned short* __restrict__ y, const unsigned* __restrict__ ebuf,
    const int* __restrict__ offs, const float* __restrict__ bias,
    float* __restrict__ out) {
  __shared__ int cnts[64];
  __shared__ int curs[64];
  __shared__ int starts[65];
  __shared__ int sorted[SORT_CAP];
  __shared__ unsigned ec[SORT_CAP];
  __shared__ int wsum2[4];
  __shared__ int segtot;

  int b = blockIdx.x;
  int t = threadIdx.x;
  if (t < 64) cnts[t] = 0;

  // ---- phase A: segment lengths (391 segs, 2 per thread) + block scan ----
  int s0a = 0, l0 = 0, s0b = 0, l1 = 0;
  {
    const int* orow = offs + (size_t)t * OFFS_W;          // t < 256 <= 390
    s0a = orow[b];
    l0 = orow[b + 1] - s0a;
  }
  if (t + 256 < BIN_BLOCKS) {
    const int* orow = offs + (size_t)(t + 256) * OFFS_W;
    s0b = orow[b];
    l1 = orow[b + 1] - s0b;
  }
  int myLen = l0 + l1;
  int lane = t & 63, wid = t >> 6;
  int v = myLen;
#pragma unroll
  for (int off = 1; off < 64; off <<= 1) {
    int n = __shfl_up(v, off);
    if (lane >= off) v += n;
  }
  if (lane == 63) wsum2[wid] = v;
  __syncthreads();
  int wbase = 0;
  for (int w2 = 0; w2 < wid; ++w2) wbase += wsum2[w2];
  int base = wbase + v - myLen;
  if (t == 255) segtot = wbase + v;

  // ---- phase B: copy my segments into the compact LDS edge list ----
  {
    const unsigned* sega = ebuf + (size_t)t * BIN_CHUNK + s0a;
    for (int j = 0; j < l0; ++j) {
      int p = base + j;
      if (p < SORT_CAP) ec[p] = sega[j];
    }
    const unsigned* segb = ebuf + (size_t)(t + 256) * BIN_CHUNK + s0b;
    for (int j = 0; j < l1; ++j) {
      int p = base + l0 + j;
      if (p < SORT_CAP) ec[p] = segb[j];
    }
  }
  __syncthreads();

  int cnt = segtot;
  if (cnt > SORT_CAP) cnt = SORT_CAP;

  // ---- counting sort by local dst (LDS only) ----
  for (int i = t; i < cnt; i += 256) atomicAdd(&cnts[ec[i] & 63u], 1);
  __syncthreads();

  if (t < 64) {
    int c = cnts[t];
    int vv = c;
#pragma unroll
    for (int off = 1; off < 64; off <<= 1) {
      int n = __shfl_up(vv, off);
      if (t >= off) vv += n;
    }
    starts[t] = vv - c;
    curs[t] = vv - c;
    if (t == 63) starts[64] = vv;
  }
  __syncthreads();

  for (int i = t; i < cnt; i += 256) {
    unsigned u = ec[i];
    int p = atomicAdd(&curs[u & 63u], 1);
    sorted[p] = (int)(u >> 6);
  }
  __syncthreads();

  // ---- column-quarter register gather ----
  int wv = t >> 6;
  int g16 = lane >> 2;   // edge slot 0..15
  int l4 = lane & 3;     // 16B chunk within the 64B quarter
#pragma unroll 1
  for (int q = 0; q < 4; ++q) {
    int c0 = q * 32 + l4 * 8;            // first col of my 8-col chunk
    float4 bv0 = *(const float4*)(bias + c0);
    float4 bv1 = *(const float4*)(bias + c0 + 4);
    for (int n = wv; n < 64; n += 4) {
      int node = b * 64 + n;
      int beg = starts[n];
      int end = starts[n + 1];
      float acc[8] = {0.f, 0.f, 0.f, 0.f, 0.f, 0.f, 0.f, 0.f};
      int i = beg + g16;
      for (; i + 16 < end; i += 32) {
        int s0e = sorted[i];
        int s1e = sorted[i + 16];
        uint4 u0 = *(const uint4*)(y + (size_t)s0e * D + c0);
        uint4 u1 = *(const uint4*)(y + (size_t)s1e * D + c0);
        acc[0] += bf2f_lo(u0.x) + bf2f_lo(u1.x);
        acc[1] += bf2f_hi(u0.x) + bf2f_hi(u1.x);
        acc[2] += bf2f_lo(u0.y) + bf2f_lo(u1.y);
        acc[3] += bf2f_hi(u0.y) + bf2f_hi(u1.y);
        acc[4] += bf2f_lo(u0.z) + bf2f_lo(u1.z);
        acc[5] += bf2f_hi(u0.z) + bf2f_hi(u1.z);
        acc[6] += bf2f_lo(u0.w) + bf2f_lo(u1.w);
        acc[7] += bf2f_hi(u0.w) + bf2f_hi(u1.w);
      }
      for (; i < end; i += 16) {
        int s = sorted[i];
        uint4 u = *(const uint4*)(y + (size_t)s * D + c0);
        acc[0] += bf2f_lo(u.x); acc[1] += bf2f_hi(u.x);
        acc[2] += bf2f_lo(u.y); acc[3] += bf2f_hi(u.y);
        acc[4] += bf2f_lo(u.z); acc[5] += bf2f_hi(u.z);
        acc[6] += bf2f_lo(u.w); acc[7] += bf2f_hi(u.w);
      }
#pragma unroll
      for (int j = 0; j < 8; ++j) {
        acc[j] += __shfl_xor(acc[j], 4);
        acc[j] += __shfl_xor(acc[j], 8);
        acc[j] += __shfl_xor(acc[j], 16);
        acc[j] += __shfl_xor(acc[j], 32);
      }
      if (g16 == 0 && node < N_NODES) {
        float4 r0 = {acc[0] + bv0.x, acc[1] + bv0.y, acc[2] + bv0.z, acc[3] + bv0.w};
        float4 r1 = {acc[4] + bv1.x, acc[5] + bv1.y, acc[6] + bv1.z, acc[7] + bv1.w};
        float* op = out + (size_t)node * D + c0;
        *(float4*)op = r0;
        *(float4*)(op + 4) = r1;
      }
    }
  }
}

// ===========================================================================
// Fallback tier 1: CSR path (R5)
// ===========================================================================
__global__ __launch_bounds__(256) void hist_kernel(
    const int* __restrict__ dst, int* __restrict__ counts) {
  int e = blockIdx.x * 256 + threadIdx.x;
  if (e < N_EDGES) atomicAdd(&counts[dst[e]], 1);
}

#define SBLK 196
__global__ __launch_bounds__(256) void reduce_kernel(
    const int* __restrict__ counts, int* __restrict__ blockSums) {
  int i = blockIdx.x * 256 + threadIdx.x;
  int v = (i < N_NODES) ? counts[i] : 0;
#pragma unroll
  for (int off = 32; off; off >>= 1) v += __shfl_down(v, off);
  __shared__ int ws[4];
  int lane = threadIdx.x & 63, wid = threadIdx.x >> 6;
  if (lane == 0) ws[wid] = v;
  __syncthreads();
  if (threadIdx.x == 0) blockSums[blockIdx.x] = ws[0] + ws[1] + ws[2] + ws[3];
}

__global__ __launch_bounds__(256) void scan_kernel2(
    const int* __restrict__ counts, const int* __restrict__ blockSums,
    int* __restrict__ offsets, int* __restrict__ cursor) {
  int b = blockIdx.x;
  int t = threadIdx.x;
  int lane = t & 63, wid = t >> 6;
  int pv = (t < b) ? blockSums[t] : 0;
#pragma unroll
  for (int off = 32; off; off >>= 1) pv += __shfl_down(pv, off);
  __shared__ int ws[4];
  __shared__ int wsum[4];
  __shared__ int base_s;
  if (lane == 0) ws[wid] = pv;
  __syncthreads();
  if (t == 0) base_s = ws[0] + ws[1] + ws[2] + ws[3];
  int i = b * 256 + t;
  int c = (i < N_NODES) ? counts[i] : 0;
  int v = c;
#pragma unroll
  for (int off = 1; off < 64; off <<= 1) {
    int n = __shfl_up(v, off);
    if (lane >= off) v += n;
  }
  if (lane == 63) wsum[wid] = v;
  __syncthreads();
  int wbase = 0;
  for (int w2 = 0; w2 < wid; ++w2) wbase += wsum[w2];
  int excl = base_s + wbase + v - c;
  if (i < N_NODES) {
    offsets[i] = excl;
    cursor[i] = excl;
    if (i == N_NODES - 1) offsets[N_NODES] = excl + c;
  }
}

__global__ __launch_bounds__(256) void fill_kernel(
    const int* __restrict__ src, const int* __restrict__ dst,
    int* __restrict__ cursor, int* __restrict__ esrc) {
  int e = blockIdx.x * 256 + threadIdx.x;
  if (e >= N_EDGES) return;
  int pos = atomicAdd(&cursor[dst[e]], 1);
  esrc[pos] = src[e];
}

__global__ __launch_bounds__(256) void gemm_xw(
    const float* __restrict__ x, const float* __restrict__ W,
    unsigned short* __restrict__ y) {
  __shared__ unsigned short As[64 * LDA];
  __shared__ unsigned short Ws[128 * LDA];
  int t = threadIdx.x;
  int row0 = blockIdx.x * 64;
  for (int i = t; i < 2048; i += 256) {
    int r = i >> 5;
    int c4 = (i & 31) * 4;
    int gr = row0 + r;
    float4 v = (gr < N_NODES) ? *(const float4*)(x + (size_t)gr * D + c4)
                              : float4{0.f, 0.f, 0.f, 0.f};
    *(uint2*)&As[r * LDA + c4] = pack4bf(v);
  }
  for (int i = t; i < 4096; i += 256) {
    int r = i >> 5;
    int c4 = (i & 31) * 4;
    float4 wv = *(const float4*)(W + (size_t)r * D + c4);
    *(uint2*)&Ws[r * LDA + c4] = pack4bf(wv);
  }
  __syncthreads();
  int w = t >> 6;
  int lane = t & 63;
  int ln = lane & 15;
  int quad = lane >> 4;
  floatx4 acc[8];
#pragma unroll
  for (int n = 0; n < 8; ++n) acc[n] = floatx4{0.f, 0.f, 0.f, 0.f};
#pragma unroll
  for (int ks = 0; ks < 4; ++ks) {
    int kc = ks * 32 + quad * 8;
    bf16x8 a = *(const bf16x8*)&As[(w * 16 + ln) * LDA + kc];
#pragma unroll
    for (int n = 0; n < 8; ++n) {
      bf16x8 bf = *(const bf16x8*)&Ws[(n * 16 + ln) * LDA + kc];
      acc[n] = __builtin_amdgcn_mfma_f32_16x16x32_bf16(a, bf, acc[n], 0, 0, 0);
    }
  }
  int gr0 = row0 + w * 16 + quad * 4;
#pragma unroll
  for (int n = 0; n < 8; ++n) {
    int gc = n * 16 + ln;
#pragma unroll
    for (int r = 0; r < 4; ++r) {
      int gr = gr0 + r;
      if (gr < N_NODES) y[(size_t)gr * D + gc] = f2bf(acc[n][r]);
    }
  }
}

__global__ __launch_bounds__(256) void gather_ybf_kernel(
    const unsigned short* __restrict__ y, const int* __restrict__ esrc,
    const int* __restrict__ offsets, const float* __restrict__ bias,
    float* __restrict__ out) {
  int node = blockIdx.x * 4 + (threadIdx.x >> 6);
  if (node >= N_NODES) return;
  int lane = threadIdx.x & 63;
  int g = lane >> 4;
  int l = lane & 15;
  int beg = offsets[node];
  int end = offsets[node + 1];
  float acc[8] = {0.f, 0.f, 0.f, 0.f, 0.f, 0.f, 0.f, 0.f};
  int i = beg + g;
  for (; i + 4 < end; i += 8) {
    int s0 = esrc[i];
    int s1 = esrc[i + 4];
    uint4 u0 = *(const uint4*)(y + (size_t)s0 * D + l * 8);
    uint4 u1 = *(const uint4*)(y + (size_t)s1 * D + l * 8);
    acc[0] += bf2f_lo(u0.x) + bf2f_lo(u1.x);
    acc[1] += bf2f_hi(u0.x) + bf2f_hi(u1.x);
    acc[2] += bf2f_lo(u0.y) + bf2f_lo(u1.y);
    acc[3] += bf2f_hi(u0.y) + bf2f_hi(u1.y);
    acc[4] += bf2f_lo(u0.z) + bf2f_lo(u1.z);
    acc[5] += bf2f_hi(u0.z) + bf2f_hi(u1.z);
    acc[6] += bf2f_lo(u0.w) + bf2f_lo(u1.w);
    acc[7] += bf2f_hi(u0.w) + bf2f_hi(u1.w);
  }
  if (i < end) {
    int s = esrc[i];
    uint4 u = *(const uint4*)(y + (size_t)s * D + l * 8);
    acc[0] += bf2f_lo(u.x); acc[1] += bf2f_hi(u.x);
    acc[2] += bf2f_lo(u.y); acc[3] += bf2f_hi(u.y);
    acc[4] += bf2f_lo(u.z); acc[5] += bf2f_hi(u.z);
    acc[6] += bf2f_lo(u.w); acc[7] += bf2f_hi(u.w);
  }
#pragma unroll
  for (int j = 0; j < 8; ++j) {
    acc[j] += __shfl_xor(acc[j], 16);
    acc[j] += __shfl_xor(acc[j], 32);
  }
  if (g == 0) {
    const float* bp = bias + l * 8;
    float4 r0 = {acc[0] + bp[0], acc[1] + bp[1], acc[2] + bp[2], acc[3] + bp[3]};
    float4 r1 = {acc[4] + bp[4], acc[5] + bp[5], acc[6] + bp[6], acc[7] + bp[7]};
    float* op = out + (size_t)node * D + l * 8;
    *(float4*)op = r0;
    *(float4*)(op + 4) = r1;
  }
}

// ===========================================================================
// Fallback tier 2: atomic scatter + f32 transform.
// ===========================================================================
__global__ __launch_bounds__(256) void scatter_kernel(
    const float* __restrict__ x, const int* __restrict__ src,
    const int* __restrict__ dst, float* __restrict__ out) {
  int gtid = blockIdx.x * 256 + threadIdx.x;
  int e = gtid >> 6;
  int lane = threadIdx.x & 63;
  if (e >= N_EDGES) return;
  float2 v = ((const float2*)(x + (size_t)src[e] * D))[lane];
  float* orow = out + (size_t)dst[e] * D + lane * 2;
  atomicAdd(orow + 0, v.x);
  atomicAdd(orow + 1, v.y);
}

__global__ __launch_bounds__(256) void transform_kernel(
    float* __restrict__ out, const float* __restrict__ W,
    const float* __restrict__ bias) {
  constexpr int RPB = 64;
  constexpr int HP = 132;
  __shared__ float Hs[RPB][HP];
  int t = threadIdx.x;
  int row0 = blockIdx.x * RPB;
  int nr = min(RPB, N_NODES - row0);
  {
    const float4* g = (const float4*)(out + (size_t)row0 * D);
    for (int i = t; i < nr * (D / 4); i += 256) {
      int r = i >> 5;
      int c = (i & 31) * 4;
      *(float4*)&Hs[r][c] = g[i];
    }
  }
  __syncthreads();
  int tx = t & 15;
  int ty = t >> 4;
  int r0 = ty * 4;
  for (int half = 0; half < 2; ++half) {
    int oc0 = half * 64 + tx * 4;
    const float* Wb = W + (size_t)oc0 * D;
    float4 a0 = {0.f, 0.f, 0.f, 0.f}, a1 = {0.f, 0.f, 0.f, 0.f};
    float4 a2 = {0.f, 0.f, 0.f, 0.f}, a3 = {0.f, 0.f, 0.f, 0.f};
#pragma unroll 8
    for (int k = 0; k < D; k += 4) {
      float4 w0 = *(const float4*)(Wb + 0 * D + k);
      float4 w1 = *(const float4*)(Wb + 1 * D + k);
      float4 w2 = *(const float4*)(Wb + 2 * D + k);
      float4 w3 = *(const float4*)(Wb + 3 * D + k);
      float4 h0 = *(const float4*)&Hs[r0 + 0][k];
      float4 h1 = *(const float4*)&Hs[r0 + 1][k];
      float4 h2 = *(const float4*)&Hs[r0 + 2][k];
      float4 h3 = *(const float4*)&Hs[r0 + 3][k];
#define DOT(hv, wv) fmaf((hv).w, (wv).w, fmaf((hv).z, (wv).z, fmaf((hv).y, (wv).y, (hv).x * (wv).x)))
      a0.x += DOT(h0, w0); a0.y += DOT(h0, w1); a0.z += DOT(h0, w2); a0.w += DOT(h0, w3);
      a1.x += DOT(h1, w0); a1.y += DOT(h1, w1); a1.z += DOT(h1, w2); a1.w += DOT(h1, w3);
      a2.x += DOT(h2, w0); a2.y += DOT(h2, w1); a2.z += DOT(h2, w2); a2.w += DOT(h2, w3);
      a3.x += DOT(h3, w0); a3.y += DOT(h3, w1); a3.z += DOT(h3, w2); a3.w += DOT(h3, w3);
#undef DOT
    }
    float4 bv = *(const float4*)(bias + oc0);
    a0.x += bv.x; a0.y += bv.y; a0.z += bv.z; a0.w += bv.w;
    a1.x += bv.x; a1.y += bv.y; a1.z += bv.z; a1.w += bv.w;
    a2.x += bv.x; a2.y += bv.y; a2.z += bv.z; a2.w += bv.w;
    a3.x += bv.x; a3.y += bv.y; a3.z += bv.z; a3.w += bv.w;
    if (r0 + 0 < nr) *(float4*)(out + (size_t)(row0 + r0 + 0) * D + oc0) = a0;
    if (r0 + 1 < nr) *(float4*)(out + (size_t)(row0 + r0 + 1) * D + oc0) = a1;
    if (r0 + 2 < nr) *(float4*)(out + (size_t)(row0 + r0 + 2) * D + oc0) = a2;
    if (r0 + 3 < nr) *(float4*)(out + (size_t)(row0 + r0 + 3) * D + oc0) = a3;
  }
}

extern "C" void kernel_launch(void* const* d_in, const int* in_sizes, int n_in,
                              void* d_out, int out_size, void* d_ws, size_t ws_size,
                              hipStream_t stream) {
  const float* x = (const float*)d_in[0];
  const int* src = (const int*)d_in[1];
  const int* dst = (const int*)d_in[2];
  const float* W = (const float*)d_in[3];
  const float* b = (const float*)d_in[4];
  float* out = (float*)d_out;

  const size_t ybytes = (size_t)N_NODES * D * sizeof(unsigned short);      // 12.8 MB
  const size_t ebytes = (size_t)BIN_BLOCKS * BIN_CHUNK * sizeof(unsigned); // 3.2 MB
  const size_t obytes = (size_t)BIN_BLOCKS * OFFS_W * sizeof(int);         // 1.2 MB
  const size_t wbytes = (size_t)D * D * sizeof(unsigned short);            // 32 KB

  if (ws_size >= ybytes + ebytes + obytes + wbytes) {
    unsigned short* y = (unsigned short*)d_ws;
    unsigned* ebuf = (unsigned*)((char*)d_ws + ybytes);
    int* offs = (int*)((char*)ebuf + ebytes);
    unsigned short* wbf = (unsigned short*)((char*)offs + obytes);

    wconv_kernel<<<16, 256, 0, stream>>>(W, wbf);
    prep_kernel<<<BIN_BLOCKS + NB, 256, 0, stream>>>(x, wbf, y, src, dst, ebuf, offs);
    gather_sorted<<<NB, 256, 0, stream>>>(y, ebuf, offs, b, out);
    return;
  }

  const size_t A = 50048;
  const size_t head_ints = 3 * A + 256 + (size_t)N_EDGES;
  const size_t need_csr = head_ints * sizeof(int) + ybytes;

  if (ws_size >= need_csr) {
    int* counts     = (int*)d_ws;
    int* offsets    = counts + A;
    int* cursor     = offsets + A;
    int* blockSums  = cursor + A;
    int* esrc       = blockSums + 256;
    unsigned short* y = (unsigned short*)(esrc + N_EDGES);

    hipMemsetAsync(counts, 0, N_NODES * sizeof(int), stream);
    hist_kernel<<<(N_EDGES + 255) / 256, 256, 0, stream>>>(dst, counts);
    reduce_kernel<<<SBLK, 256, 0, stream>>>(counts, blockSums);
    scan_kernel2<<<SBLK, 256, 0, stream>>>(counts, blockSums, offsets, cursor);
    fill_kernel<<<(N_EDGES + 255) / 256, 256, 0, stream>>>(src, dst, cursor, esrc);
    gemm_xw<<<NB, 256, 0, stream>>>(x, W, y);
    gather_ybf_kernel<<<(N_NODES + 3) / 4, 256, 0, stream>>>(y, esrc, offsets, b, out);
  } else {
    hipMemsetAsync(out, 0, (size_t)N_NODES * D * sizeof(float), stream);
    scatter_kernel<<<N_EDGES / 4, 256, 0, stream>>>(x, src, dst, out);
    transform_kernel<<<(N_NODES + 63) / 64, 256, 0, stream>>>(out, W, b);
  }
}

// Round 6
// 146.854 us; speedup vs baseline: 1.4623x; 1.4623x over previous
//
#include <hip/hip_runtime.h>

#define N_NODES 50000
#define N_EDGES 800000
#define D 128
#define NB 782            // ceil(50000/64) buckets of 64 nodes
#define SORT_CAP 2048

typedef __attribute__((ext_vector_type(8))) short bf16x8;   // MFMA A/B frag
typedef __attribute__((ext_vector_type(4))) float floatx4;  // MFMA C/D frag

__device__ __forceinline__ unsigned short f2bf(float f) {
  unsigned u = __builtin_bit_cast(unsigned, f);
  unsigned r = u + 0x7FFFu + ((u >> 16) & 1u);  // RNE
  return (unsigned short)(r >> 16);
}
__device__ __forceinline__ float bf2f_lo(unsigned u) {
  return __builtin_bit_cast(float, u << 16);
}
__device__ __forceinline__ float bf2f_hi(unsigned u) {
  return __builtin_bit_cast(float, u & 0xFFFF0000u);
}
__device__ __forceinline__ uint2 pack4bf(float4 v) {
  unsigned a = f2bf(v.x), b = f2bf(v.y), c = f2bf(v.z), d = f2bf(v.w);
  return uint2{a | (b << 16), c | (d << 16)};
}

// ===========================================================================
// wconv: one-shot W f32 -> bf16 (32 KB), L1-resident for all gemm tiles.
// ===========================================================================
__global__ __launch_bounds__(256) void wconv_kernel(
    const float* __restrict__ W, unsigned short* __restrict__ wbf) {
  int i = blockIdx.x * 256 + threadIdx.x;   // 16 blocks * 256t * 4 = 16384
  float4 v = *(const float4*)(W + (size_t)i * 4);
  *(uint2*)(wbf + (size_t)i * 4) = pack4bf(v);
}

// ===========================================================================
// prep_kernel: fused [bin blocks | gemm tiles] in one grid.
// R14: BIN_CHUNK 2048 (391 bin blocks) -- halves each bin block's SERIAL
// critical path (hist atomics + scatter); prep was stuck ~40us at chunk 4096
// with ~1 bin block/CU.  gather reverted to the proven full-row form.
// ===========================================================================
#define LDA 136
#define BIN_T 256
#define BIN_CHUNK 2048
#define BIN_BLOCKS 391   // 391*2048 = 800768 >= 800000 (last block partial)
#define OFFS_W 783       // 782 bucket starts + total

struct BinShm {
  unsigned stage[BIN_CHUNK];   // 8 KB
  int hcnt[NB];
  int hstart[NB];
  int hcur[NB];
  int wsums[4];
  int tot;
};
struct GemmShm {
  unsigned short As[64 * LDA];    // 17.4 KB
};
union PrepShm {
  BinShm bin;
  GemmShm gemm;
};

__global__ __launch_bounds__(256) void prep_kernel(
    const float* __restrict__ x, const unsigned short* __restrict__ wbf,
    unsigned short* __restrict__ y,
    const int* __restrict__ src, const int* __restrict__ dst,
    unsigned* __restrict__ ebuf, int* __restrict__ offs) {
  __shared__ PrepShm shm;
  int t = threadIdx.x;

  if (blockIdx.x >= BIN_BLOCKS) {
    // ---------------- GEMM tile: y[row0..row0+64) = bf16(x @ W^T) ----------
    unsigned short* As = shm.gemm.As;
    int row0 = (blockIdx.x - BIN_BLOCKS) * 64;

    for (int i = t; i < 2048; i += 256) {
      int r = i >> 5;
      int c4 = (i & 31) * 4;
      int gr = row0 + r;
      float4 v = (gr < N_NODES) ? *(const float4*)(x + (size_t)gr * D + c4)
                                : float4{0.f, 0.f, 0.f, 0.f};
      *(uint2*)&As[r * LDA + c4] = pack4bf(v);
    }
    __syncthreads();

    int w = t >> 6;
    int lane = t & 63;
    int ln = lane & 15;
    int quad = lane >> 4;

    floatx4 acc[8];
#pragma unroll
    for (int n = 0; n < 8; ++n) acc[n] = floatx4{0.f, 0.f, 0.f, 0.f};

#pragma unroll
    for (int ks = 0; ks < 4; ++ks) {
      int kc = ks * 32 + quad * 8;
      bf16x8 a = *(const bf16x8*)&As[(w * 16 + ln) * LDA + kc];
#pragma unroll
      for (int n = 0; n < 8; ++n) {
        bf16x8 bf = *(const bf16x8*)&wbf[(size_t)(n * 16 + ln) * D + kc];
        acc[n] = __builtin_amdgcn_mfma_f32_16x16x32_bf16(a, bf, acc[n], 0, 0, 0);
      }
    }

    // D layout: col = lane&15, row = quad*4 + reg.
    int gr0 = row0 + w * 16 + quad * 4;
#pragma unroll
    for (int n = 0; n < 8; ++n) {
      int gc = n * 16 + ln;
#pragma unroll
      for (int r = 0; r < 4; ++r) {
        int gr = gr0 + r;
        if (gr < N_NODES) y[(size_t)gr * D + gc] = f2bf(acc[n][r]);
      }
    }
  } else {
    // ---------------- bin block: bucket-group 2048 edges, own segment ------
    BinShm& B = shm.bin;
    int blk = blockIdx.x;
    int e0 = blk * BIN_CHUNK;
    for (int i = t; i < NB; i += BIN_T) B.hcnt[i] = 0;
    __syncthreads();

    unsigned pk[8];
    short bk[8];
#pragma unroll
    for (int j = 0; j < 8; ++j) {
      int e = e0 + j * BIN_T + t;
      bk[j] = -1;
      if (e < N_EDGES) {
        int d = dst[e];
        int s = src[e];
        pk[j] = ((unsigned)s << 6) | (unsigned)(d & 63);
        bk[j] = (short)(d >> 6);
        atomicAdd(&B.hcnt[d >> 6], 1);
      }
    }
    __syncthreads();

    // exclusive scan of hcnt[782]: 4 counters/thread (256*4=1024 >= 782)
    int c4[4];
    int s4 = 0;
    int base4 = t * 4;
#pragma unroll
    for (int j = 0; j < 4; ++j) {
      int idx = base4 + j;
      c4[j] = (idx < NB) ? B.hcnt[idx] : 0;
      s4 += c4[j];
    }
    int incl = s4;
    int lane = t & 63, wid = t >> 6;
#pragma unroll
    for (int off = 1; off < 64; off <<= 1) {
      int n = __shfl_up(incl, off);
      if (lane >= off) incl += n;
    }
    if (lane == 63) B.wsums[wid] = incl;
    __syncthreads();
    int wbase = 0;
    for (int w2 = 0; w2 < wid; ++w2) wbase += B.wsums[w2];
    int run = wbase + incl - s4;
#pragma unroll
    for (int j = 0; j < 4; ++j) {
      int idx = base4 + j;
      if (idx < NB) { B.hstart[idx] = run; B.hcur[idx] = run; }
      run += c4[j];
    }
    if (t == BIN_T - 1) B.tot = run;
    __syncthreads();

    // scatter into stage grouped by bucket (scalar LDS atomics only)
#pragma unroll
    for (int j = 0; j < 8; ++j) {
      if (bk[j] >= 0) {
        int p = atomicAdd(&B.hcur[bk[j]], 1);
        B.stage[p] = pk[j];
      }
    }
    __syncthreads();

    // flush: fully coalesced copy of this block's segment (uint4 wide)
    int tot = B.tot;
    unsigned* dseg = ebuf + (size_t)blk * BIN_CHUNK;
    int tot4 = tot >> 2;
    uint4* d4 = (uint4*)dseg;
    const uint4* s4p = (const uint4*)B.stage;
    for (int i = t; i < tot4; i += BIN_T) d4[i] = s4p[i];
    for (int i = (tot & ~3) + t; i < tot; i += BIN_T) dseg[i] = B.stage[i];

    // publish per-bucket offsets (coalesced, no atomics)
    int* orow = offs + (size_t)blk * OFFS_W;
    for (int i = t; i < NB; i += BIN_T) orow[i] = B.hstart[i];
    if (t == 0) orow[NB] = tot;
  }
}

// ===========================================================================
// gather_sorted: block per bucket, 256t, FULL-ROW gather (R10/R12-proven
// 45.4us form; R13's column-quarter version tripled time -- 64B quarters
// still pull 128B lines => 6.4MB/pass > 4MiB L2, plus 4x edge traversal).
// Stitch bucket edges from 391 segments (2/thread), in-LDS counting sort,
// wave-per-node register gather, shfl reduce, fused bias.
// ===========================================================================
__global__ __launch_bounds__(256) void gather_sorted(
    const unsigned short* __restrict__ y, const unsigned* __restrict__ ebuf,
    const int* __restrict__ offs, const float* __restrict__ bias,
    float* __restrict__ out) {
  __shared__ int cnts[64];
  __shared__ int curs[64];
  __shared__ int starts[65];
  __shared__ int sorted[SORT_CAP];
  __shared__ unsigned ec[SORT_CAP];
  __shared__ int wsum2[4];
  __shared__ int segtot;

  int b = blockIdx.x;
  int t = threadIdx.x;
  if (t < 64) cnts[t] = 0;

  // ---- phase A: segment lengths (391 segs, 2 per thread) + block scan ----
  int s0a = 0, l0 = 0, s0b = 0, l1 = 0;
  {
    const int* orow = offs + (size_t)t * OFFS_W;          // t < 256 <= 390
    s0a = orow[b];
    l0 = orow[b + 1] - s0a;
  }
  if (t + 256 < BIN_BLOCKS) {
    const int* orow = offs + (size_t)(t + 256) * OFFS_W;
    s0b = orow[b];
    l1 = orow[b + 1] - s0b;
  }
  int myLen = l0 + l1;
  int lane = t & 63, wid = t >> 6;
  int v = myLen;
#pragma unroll
  for (int off = 1; off < 64; off <<= 1) {
    int n = __shfl_up(v, off);
    if (lane >= off) v += n;
  }
  if (lane == 63) wsum2[wid] = v;
  __syncthreads();
  int wbase = 0;
  for (int w2 = 0; w2 < wid; ++w2) wbase += wsum2[w2];
  int base = wbase + v - myLen;
  if (t == 255) segtot = wbase + v;

  // ---- phase B: copy my segments into the compact LDS edge list ----
  {
    const unsigned* sega = ebuf + (size_t)t * BIN_CHUNK + s0a;
    for (int j = 0; j < l0; ++j) {
      int p = base + j;
      if (p < SORT_CAP) ec[p] = sega[j];
    }
    const unsigned* segb = ebuf + (size_t)(t + 256) * BIN_CHUNK + s0b;
    for (int j = 0; j < l1; ++j) {
      int p = base + l0 + j;
      if (p < SORT_CAP) ec[p] = segb[j];
    }
  }
  __syncthreads();

  int cnt = segtot;
  if (cnt > SORT_CAP) cnt = SORT_CAP;

  // ---- counting sort by local dst (LDS only) ----
  for (int i = t; i < cnt; i += 256) atomicAdd(&cnts[ec[i] & 63u], 1);
  __syncthreads();

  if (t < 64) {
    int c = cnts[t];
    int vv = c;
#pragma unroll
    for (int off = 1; off < 64; off <<= 1) {
      int n = __shfl_up(vv, off);
      if (t >= off) vv += n;
    }
    starts[t] = vv - c;
    curs[t] = vv - c;
    if (t == 63) starts[64] = vv;
  }
  __syncthreads();

  for (int i = t; i < cnt; i += 256) {
    unsigned u = ec[i];
    int p = atomicAdd(&curs[u & 63u], 1);
    sorted[p] = (int)(u >> 6);
  }
  __syncthreads();

  // ---- wave-per-node register gather (full 256B rows) ----
  int wv = t >> 6;
  int g = lane >> 4;   // edge subgroup 0..3
  int l = lane & 15;   // 8-col chunk within row
  float4 bv0 = *(const float4*)(bias + l * 8);
  float4 bv1 = *(const float4*)(bias + l * 8 + 4);
  for (int n = wv; n < 64; n += 4) {
    int node = b * 64 + n;
    int beg = starts[n];
    int end = starts[n + 1];
    float acc[8] = {0.f, 0.f, 0.f, 0.f, 0.f, 0.f, 0.f, 0.f};
    int i = beg + g;
    for (; i + 12 < end; i += 16) {
      int s0e = sorted[i];
      int s1e = sorted[i + 4];
      int s2e = sorted[i + 8];
      int s3e = sorted[i + 12];
      uint4 u0 = *(const uint4*)(y + (size_t)s0e * D + l * 8);
      uint4 u1 = *(const uint4*)(y + (size_t)s1e * D + l * 8);
      uint4 u2 = *(const uint4*)(y + (size_t)s2e * D + l * 8);
      uint4 u3 = *(const uint4*)(y + (size_t)s3e * D + l * 8);
      acc[0] += (bf2f_lo(u0.x) + bf2f_lo(u1.x)) + (bf2f_lo(u2.x) + bf2f_lo(u3.x));
      acc[1] += (bf2f_hi(u0.x) + bf2f_hi(u1.x)) + (bf2f_hi(u2.x) + bf2f_hi(u3.x));
      acc[2] += (bf2f_lo(u0.y) + bf2f_lo(u1.y)) + (bf2f_lo(u2.y) + bf2f_lo(u3.y));
      acc[3] += (bf2f_hi(u0.y) + bf2f_hi(u1.y)) + (bf2f_hi(u2.y) + bf2f_hi(u3.y));
      acc[4] += (bf2f_lo(u0.z) + bf2f_lo(u1.z)) + (bf2f_lo(u2.z) + bf2f_lo(u3.z));
      acc[5] += (bf2f_hi(u0.z) + bf2f_hi(u1.z)) + (bf2f_hi(u2.z) + bf2f_hi(u3.z));
      acc[6] += (bf2f_lo(u0.w) + bf2f_lo(u1.w)) + (bf2f_lo(u2.w) + bf2f_lo(u3.w));
      acc[7] += (bf2f_hi(u0.w) + bf2f_hi(u1.w)) + (bf2f_hi(u2.w) + bf2f_hi(u3.w));
    }
    for (; i < end; i += 4) {
      int s = sorted[i];
      uint4 u = *(const uint4*)(y + (size_t)s * D + l * 8);
      acc[0] += bf2f_lo(u.x); acc[1] += bf2f_hi(u.x);
      acc[2] += bf2f_lo(u.y); acc[3] += bf2f_hi(u.y);
      acc[4] += bf2f_lo(u.z); acc[5] += bf2f_hi(u.z);
      acc[6] += bf2f_lo(u.w); acc[7] += bf2f_hi(u.w);
    }
#pragma unroll
    for (int j = 0; j < 8; ++j) {
      acc[j] += __shfl_xor(acc[j], 16);
      acc[j] += __shfl_xor(acc[j], 32);
    }
    if (g == 0 && node < N_NODES) {
      float4 r0 = {acc[0] + bv0.x, acc[1] + bv0.y, acc[2] + bv0.z, acc[3] + bv0.w};
      float4 r1 = {acc[4] + bv1.x, acc[5] + bv1.y, acc[6] + bv1.z, acc[7] + bv1.w};
      float* op = out + (size_t)node * D + l * 8;
      *(float4*)op = r0;
      *(float4*)(op + 4) = r1;
    }
  }
}

// ===========================================================================
// Fallback tier 1: CSR path (R5)
// ===========================================================================
__global__ __launch_bounds__(256) void hist_kernel(
    const int* __restrict__ dst, int* __restrict__ counts) {
  int e = blockIdx.x * 256 + threadIdx.x;
  if (e < N_EDGES) atomicAdd(&counts[dst[e]], 1);
}

#define SBLK 196
__global__ __launch_bounds__(256) void reduce_kernel(
    const int* __restrict__ counts, int* __restrict__ blockSums) {
  int i = blockIdx.x * 256 + threadIdx.x;
  int v = (i < N_NODES) ? counts[i] : 0;
#pragma unroll
  for (int off = 32; off; off >>= 1) v += __shfl_down(v, off);
  __shared__ int ws[4];
  int lane = threadIdx.x & 63, wid = threadIdx.x >> 6;
  if (lane == 0) ws[wid] = v;
  __syncthreads();
  if (threadIdx.x == 0) blockSums[blockIdx.x] = ws[0] + ws[1] + ws[2] + ws[3];
}

__global__ __launch_bounds__(256) void scan_kernel2(
    const int* __restrict__ counts, const int* __restrict__ blockSums,
    int* __restrict__ offsets, int* __restrict__ cursor) {
  int b = blockIdx.x;
  int t = threadIdx.x;
  int lane = t & 63, wid = t >> 6;
  int pv = (t < b) ? blockSums[t] : 0;
#pragma unroll
  for (int off = 32; off; off >>= 1) pv += __shfl_down(pv, off);
  __shared__ int ws[4];
  __shared__ int wsum[4];
  __shared__ int base_s;
  if (lane == 0) ws[wid] = pv;
  __syncthreads();
  if (t == 0) base_s = ws[0] + ws[1] + ws[2] + ws[3];
  int i = b * 256 + t;
  int c = (i < N_NODES) ? counts[i] : 0;
  int v = c;
#pragma unroll
  for (int off = 1; off < 64; off <<= 1) {
    int n = __shfl_up(v, off);
    if (lane >= off) v += n;
  }
  if (lane == 63) wsum[wid] = v;
  __syncthreads();
  int wbase = 0;
  for (int w2 = 0; w2 < wid; ++w2) wbase += wsum[w2];
  int excl = base_s + wbase + v - c;
  if (i < N_NODES) {
    offsets[i] = excl;
    cursor[i] = excl;
    if (i == N_NODES - 1) offsets[N_NODES] = excl + c;
  }
}

__global__ __launch_bounds__(256) void fill_kernel(
    const int* __restrict__ src, const int* __restrict__ dst,
    int* __restrict__ cursor, int* __restrict__ esrc) {
  int e = blockIdx.x * 256 + threadIdx.x;
  if (e >= N_EDGES) return;
  int pos = atomicAdd(&cursor[dst[e]], 1);
  esrc[pos] = src[e];
}

__global__ __launch_bounds__(256) void gemm_xw(
    const float* __restrict__ x, const float* __restrict__ W,
    unsigned short* __restrict__ y) {
  __shared__ unsigned short As[64 * LDA];
  __shared__ unsigned short Ws[128 * LDA];
  int t = threadIdx.x;
  int row0 = blockIdx.x * 64;
  for (int i = t; i < 2048; i += 256) {
    int r = i >> 5;
    int c4 = (i & 31) * 4;
    int gr = row0 + r;
    float4 v = (gr < N_NODES) ? *(const float4*)(x + (size_t)gr * D + c4)
                              : float4{0.f, 0.f, 0.f, 0.f};
    *(uint2*)&As[r * LDA + c4] = pack4bf(v);
  }
  for (int i = t; i < 4096; i += 256) {
    int r = i >> 5;
    int c4 = (i & 31) * 4;
    float4 wv = *(const float4*)(W + (size_t)r * D + c4);
    *(uint2*)&Ws[r * LDA + c4] = pack4bf(wv);
  }
  __syncthreads();
  int w = t >> 6;
  int lane = t & 63;
  int ln = lane & 15;
  int quad = lane >> 4;
  floatx4 acc[8];
#pragma unroll
  for (int n = 0; n < 8; ++n) acc[n] = floatx4{0.f, 0.f, 0.f, 0.f};
#pragma unroll
  for (int ks = 0; ks < 4; ++ks) {
    int kc = ks * 32 + quad * 8;
    bf16x8 a = *(const bf16x8*)&As[(w * 16 + ln) * LDA + kc];
#pragma unroll
    for (int n = 0; n < 8; ++n) {
      bf16x8 bf = *(const bf16x8*)&Ws[(n * 16 + ln) * LDA + kc];
      acc[n] = __builtin_amdgcn_mfma_f32_16x16x32_bf16(a, bf, acc[n], 0, 0, 0);
    }
  }
  int gr0 = row0 + w * 16 + quad * 4;
#pragma unroll
  for (int n = 0; n < 8; ++n) {
    int gc = n * 16 + ln;
#pragma unroll
    for (int r = 0; r < 4; ++r) {
      int gr = gr0 + r;
      if (gr < N_NODES) y[(size_t)gr * D + gc] = f2bf(acc[n][r]);
    }
  }
}

__global__ __launch_bounds__(256) void gather_ybf_kernel(
    const unsigned short* __restrict__ y, const int* __restrict__ esrc,
    const int* __restrict__ offsets, const float* __restrict__ bias,
    float* __restrict__ out) {
  int node = blockIdx.x * 4 + (threadIdx.x >> 6);
  if (node >= N_NODES) return;
  int lane = threadIdx.x & 63;
  int g = lane >> 4;
  int l = lane & 15;
  int beg = offsets[node];
  int end = offsets[node + 1];
  float acc[8] = {0.f, 0.f, 0.f, 0.f, 0.f, 0.f, 0.f, 0.f};
  int i = beg + g;
  for (; i + 4 < end; i += 8) {
    int s0 = esrc[i];
    int s1 = esrc[i + 4];
    uint4 u0 = *(const uint4*)(y + (size_t)s0 * D + l * 8);
    uint4 u1 = *(const uint4*)(y + (size_t)s1 * D + l * 8);
    acc[0] += bf2f_lo(u0.x) + bf2f_lo(u1.x);
    acc[1] += bf2f_hi(u0.x) + bf2f_hi(u1.x);
    acc[2] += bf2f_lo(u0.y) + bf2f_lo(u1.y);
    acc[3] += bf2f_hi(u0.y) + bf2f_hi(u1.y);
    acc[4] += bf2f_lo(u0.z) + bf2f_lo(u1.z);
    acc[5] += bf2f_hi(u0.z) + bf2f_hi(u1.z);
    acc[6] += bf2f_lo(u0.w) + bf2f_lo(u1.w);
    acc[7] += bf2f_hi(u0.w) + bf2f_hi(u1.w);
  }
  if (i < end) {
    int s = esrc[i];
    uint4 u = *(const uint4*)(y + (size_t)s * D + l * 8);
    acc[0] += bf2f_lo(u.x); acc[1] += bf2f_hi(u.x);
    acc[2] += bf2f_lo(u.y); acc[3] += bf2f_hi(u.y);
    acc[4] += bf2f_lo(u.z); acc[5] += bf2f_hi(u.z);
    acc[6] += bf2f_lo(u.w); acc[7] += bf2f_hi(u.w);
  }
#pragma unroll
  for (int j = 0; j < 8; ++j) {
    acc[j] += __shfl_xor(acc[j], 16);
    acc[j] += __shfl_xor(acc[j], 32);
  }
  if (g == 0) {
    const float* bp = bias + l * 8;
    float4 r0 = {acc[0] + bp[0], acc[1] + bp[1], acc[2] + bp[2], acc[3] + bp[3]};
    float4 r1 = {acc[4] + bp[4], acc[5] + bp[5], acc[6] + bp[6], acc[7] + bp[7]};
    float* op = out + (size_t)node * D + l * 8;
    *(float4*)op = r0;
    *(float4*)(op + 4) = r1;
  }
}

// ===========================================================================
// Fallback tier 2: atomic scatter + f32 transform.
// ===========================================================================
__global__ __launch_bounds__(256) void scatter_kernel(
    const float* __restrict__ x, const int* __restrict__ src,
    const int* __restrict__ dst, float* __restrict__ out) {
  int gtid = blockIdx.x * 256 + threadIdx.x;
  int e = gtid >> 6;
  int lane = threadIdx.x & 63;
  if (e >= N_EDGES) return;
  float2 v = ((const float2*)(x + (size_t)src[e] * D))[lane];
  float* orow = out + (size_t)dst[e] * D + lane * 2;
  atomicAdd(orow + 0, v.x);
  atomicAdd(orow + 1, v.y);
}

__global__ __launch_bounds__(256) void transform_kernel(
    float* __restrict__ out, const float* __restrict__ W,
    const float* __restrict__ bias) {
  constexpr int RPB = 64;
  constexpr int HP = 132;
  __shared__ float Hs[RPB][HP];
  int t = threadIdx.x;
  int row0 = blockIdx.x * RPB;
  int nr = min(RPB, N_NODES - row0);
  {
    const float4* g = (const float4*)(out + (size_t)row0 * D);
    for (int i = t; i < nr * (D / 4); i += 256) {
      int r = i >> 5;
      int c = (i & 31) * 4;
      *(float4*)&Hs[r][c] = g[i];
    }
  }
  __syncthreads();
  int tx = t & 15;
  int ty = t >> 4;
  int r0 = ty * 4;
  for (int half = 0; half < 2; ++half) {
    int oc0 = half * 64 + tx * 4;
    const float* Wb = W + (size_t)oc0 * D;
    float4 a0 = {0.f, 0.f, 0.f, 0.f}, a1 = {0.f, 0.f, 0.f, 0.f};
    float4 a2 = {0.f, 0.f, 0.f, 0.f}, a3 = {0.f, 0.f, 0.f, 0.f};
#pragma unroll 8
    for (int k = 0; k < D; k += 4) {
      float4 w0 = *(const float4*)(Wb + 0 * D + k);
      float4 w1 = *(const float4*)(Wb + 1 * D + k);
      float4 w2 = *(const float4*)(Wb + 2 * D + k);
      float4 w3 = *(const float4*)(Wb + 3 * D + k);
      float4 h0 = *(const float4*)&Hs[r0 + 0][k];
      float4 h1 = *(const float4*)&Hs[r0 + 1][k];
      float4 h2 = *(const float4*)&Hs[r0 + 2][k];
      float4 h3 = *(const float4*)&Hs[r0 + 3][k];
#define DOT(hv, wv) fmaf((hv).w, (wv).w, fmaf((hv).z, (wv).z, fmaf((hv).y, (wv).y, (hv).x * (wv).x)))
      a0.x += DOT(h0, w0); a0.y += DOT(h0, w1); a0.z += DOT(h0, w2); a0.w += DOT(h0, w3);
      a1.x += DOT(h1, w0); a1.y += DOT(h1, w1); a1.z += DOT(h1, w2); a1.w += DOT(h1, w3);
      a2.x += DOT(h2, w0); a2.y += DOT(h2, w1); a2.z += DOT(h2, w2); a2.w += DOT(h2, w3);
      a3.x += DOT(h3, w0); a3.y += DOT(h3, w1); a3.z += DOT(h3, w2); a3.w += DOT(h3, w3);
#undef DOT
    }
    float4 bv = *(const float4*)(bias + oc0);
    a0.x += bv.x; a0.y += bv.y; a0.z += bv.z; a0.w += bv.w;
    a1.x += bv.x; a1.y += bv.y; a1.z += bv.z; a1.w += bv.w;
    a2.x += bv.x; a2.y += bv.y; a2.z += bv.z; a2.w += bv.w;
    a3.x += bv.x; a3.y += bv.y; a3.z += bv.z; a3.w += bv.w;
    if (r0 + 0 < nr) *(float4*)(out + (size_t)(row0 + r0 + 0) * D + oc0) = a0;
    if (r0 + 1 < nr) *(float4*)(out + (size_t)(row0 + r0 + 1) * D + oc0) = a1;
    if (r0 + 2 < nr) *(float4*)(out + (size_t)(row0 + r0 + 2) * D + oc0) = a2;
    if (r0 + 3 < nr) *(float4*)(out + (size_t)(row0 + r0 + 3) * D + oc0) = a3;
  }
}

extern "C" void kernel_launch(void* const* d_in, const int* in_sizes, int n_in,
                              void* d_out, int out_size, void* d_ws, size_t ws_size,
                              hipStream_t stream) {
  const float* x = (const float*)d_in[0];
  const int* src = (const int*)d_in[1];
  const int* dst = (const int*)d_in[2];
  const float* W = (const float*)d_in[3];
  const float* b = (const float*)d_in[4];
  float* out = (float*)d_out;

  const size_t ybytes = (size_t)N_NODES * D * sizeof(unsigned short);      // 12.8 MB
  const size_t ebytes = (size_t)BIN_BLOCKS * BIN_CHUNK * sizeof(unsigned); // 3.2 MB
  const size_t obytes = (size_t)BIN_BLOCKS * OFFS_W * sizeof(int);         // 1.2 MB
  const size_t wbytes = (size_t)D * D * sizeof(unsigned short);            // 32 KB

  if (ws_size >= ybytes + ebytes + obytes + wbytes) {
    unsigned short* y = (unsigned short*)d_ws;
    unsigned* ebuf = (unsigned*)((char*)d_ws + ybytes);
    int* offs = (int*)((char*)ebuf + ebytes);
    unsigned short* wbf = (unsigned short*)((char*)offs + obytes);

    wconv_kernel<<<16, 256, 0, stream>>>(W, wbf);
    prep_kernel<<<BIN_BLOCKS + NB, 256, 0, stream>>>(x, wbf, y, src, dst, ebuf, offs);
    gather_sorted<<<NB, 256, 0, stream>>>(y, ebuf, offs, b, out);
    return;
  }

  const size_t A = 50048;
  const size_t head_ints = 3 * A + 256 + (size_t)N_EDGES;
  const size_t need_csr = head_ints * sizeof(int) + ybytes;

  if (ws_size >= need_csr) {
    int* counts     = (int*)d_ws;
    int* offsets    = counts + A;
    int* cursor     = offsets + A;
    int* blockSums  = cursor + A;
    int* esrc       = blockSums + 256;
    unsigned short* y = (unsigned short*)(esrc + N_EDGES);

    hipMemsetAsync(counts, 0, N_NODES * sizeof(int), stream);
    hist_kernel<<<(N_EDGES + 255) / 256, 256, 0, stream>>>(dst, counts);
    reduce_kernel<<<SBLK, 256, 0, stream>>>(counts, blockSums);
    scan_kernel2<<<SBLK, 256, 0, stream>>>(counts, blockSums, offsets, cursor);
    fill_kernel<<<(N_EDGES + 255) / 256, 256, 0, stream>>>(src, dst, cursor, esrc);
    gemm_xw<<<NB, 256, 0, stream>>>(x, W, y);
    gather_ybf_kernel<<<(N_NODES + 3) / 4, 256, 0, stream>>>(y, esrc, offsets, b, out);
  } else {
    hipMemsetAsync(out, 0, (size_t)N_NODES * D * sizeof(float), stream);
    scatter_kernel<<<N_EDGES / 4, 256, 0, stream>>>(x, src, dst, out);
    transform_kernel<<<(N_NODES + 63) / 64, 256, 0, stream>>>(out, W, b);
  }
}

// Round 7
// 137.076 us; speedup vs baseline: 1.5666x; 1.0713x over previous
//
#include <hip/hip_runtime.h>

#define N_NODES 50000
#define N_EDGES 800000
#define D 128
#define NB 782            // gemm tiles of 64 rows (and tier-1 fallback)
#define NBK 1563          // ceil(50000/32) gather buckets of 32 nodes
#define SORT_CAP 1024     // bucket mean 512, +22 sigma

typedef __attribute__((ext_vector_type(8))) short bf16x8;   // MFMA A/B frag
typedef __attribute__((ext_vector_type(4))) float floatx4;  // MFMA C/D frag

__device__ __forceinline__ unsigned short f2bf(float f) {
  unsigned u = __builtin_bit_cast(unsigned, f);
  unsigned r = u + 0x7FFFu + ((u >> 16) & 1u);  // RNE
  return (unsigned short)(r >> 16);
}
__device__ __forceinline__ float bf2f_lo(unsigned u) {
  return __builtin_bit_cast(float, u << 16);
}
__device__ __forceinline__ float bf2f_hi(unsigned u) {
  return __builtin_bit_cast(float, u & 0xFFFF0000u);
}
__device__ __forceinline__ uint2 pack4bf(float4 v) {
  unsigned a = f2bf(v.x), b = f2bf(v.y), c = f2bf(v.z), d = f2bf(v.w);
  return uint2{a | (b << 16), c | (d << 16)};
}

// ===========================================================================
// wconv: one-shot W f32 -> bf16 (32 KB), L1-resident for all gemm tiles.
// ===========================================================================
__global__ __launch_bounds__(256) void wconv_kernel(
    const float* __restrict__ W, unsigned short* __restrict__ wbf) {
  int i = blockIdx.x * 256 + threadIdx.x;   // 16 blocks * 256t * 4 = 16384
  float4 v = *(const float4*)(W + (size_t)i * 4);
  *(uint2*)(wbf + (size_t)i * 4) = pack4bf(v);
}

// ===========================================================================
// prep_kernel: fused [bin blocks | gemm tiles].  R15: buckets of 32 nodes
// (1563) so gather gets 6.1 blocks/CU (was 3.05, 24% occupancy -- grid-
// limited TLP was gather's bottleneck, R11's 512t kept 1.5 blocks/CU and
// regressed).  BIN_CHUNK back to 4096 (2048 was neutral, R14).
// ===========================================================================
#define LDA 136
#define BIN_T 256
#define BIN_CHUNK 4096
#define BIN_BLOCKS 196   // 196*4096 = 802816 >= 800000 (last block partial)
#define OFFS_W 1564      // 1563 bucket starts + total

struct BinShm {
  unsigned stage[BIN_CHUNK];   // 16 KB
  int hcnt[NBK];
  int hstart[NBK];
  int hcur[NBK];
  int wsums[4];
  int tot;
};
struct GemmShm {
  unsigned short As[64 * LDA];    // 17.4 KB
};
union PrepShm {
  BinShm bin;
  GemmShm gemm;
};

__global__ __launch_bounds__(256) void prep_kernel(
    const float* __restrict__ x, const unsigned short* __restrict__ wbf,
    unsigned short* __restrict__ y,
    const int* __restrict__ src, const int* __restrict__ dst,
    unsigned* __restrict__ ebuf, int* __restrict__ offs) {
  __shared__ PrepShm shm;
  int t = threadIdx.x;

  if (blockIdx.x >= BIN_BLOCKS) {
    // ---------------- GEMM tile: y[row0..row0+64) = bf16(x @ W^T) ----------
    unsigned short* As = shm.gemm.As;
    int row0 = (blockIdx.x - BIN_BLOCKS) * 64;

    for (int i = t; i < 2048; i += 256) {
      int r = i >> 5;
      int c4 = (i & 31) * 4;
      int gr = row0 + r;
      float4 v = (gr < N_NODES) ? *(const float4*)(x + (size_t)gr * D + c4)
                                : float4{0.f, 0.f, 0.f, 0.f};
      *(uint2*)&As[r * LDA + c4] = pack4bf(v);
    }
    __syncthreads();

    int w = t >> 6;
    int lane = t & 63;
    int ln = lane & 15;
    int quad = lane >> 4;

    floatx4 acc[8];
#pragma unroll
    for (int n = 0; n < 8; ++n) acc[n] = floatx4{0.f, 0.f, 0.f, 0.f};

#pragma unroll
    for (int ks = 0; ks < 4; ++ks) {
      int kc = ks * 32 + quad * 8;
      bf16x8 a = *(const bf16x8*)&As[(w * 16 + ln) * LDA + kc];
#pragma unroll
      for (int n = 0; n < 8; ++n) {
        bf16x8 bf = *(const bf16x8*)&wbf[(size_t)(n * 16 + ln) * D + kc];
        acc[n] = __builtin_amdgcn_mfma_f32_16x16x32_bf16(a, bf, acc[n], 0, 0, 0);
      }
    }

    // D layout: col = lane&15, row = quad*4 + reg.
    int gr0 = row0 + w * 16 + quad * 4;
#pragma unroll
    for (int n = 0; n < 8; ++n) {
      int gc = n * 16 + ln;
#pragma unroll
      for (int r = 0; r < 4; ++r) {
        int gr = gr0 + r;
        if (gr < N_NODES) y[(size_t)gr * D + gc] = f2bf(acc[n][r]);
      }
    }
  } else {
    // ---------------- bin block: bucket-group 4096 edges, own segment ------
    BinShm& B = shm.bin;
    int blk = blockIdx.x;
    int e0 = blk * BIN_CHUNK;
    for (int i = t; i < NBK; i += BIN_T) B.hcnt[i] = 0;
    __syncthreads();

    unsigned pk[16];
    short bk[16];
#pragma unroll
    for (int j = 0; j < 16; ++j) {
      int e = e0 + j * BIN_T + t;
      bk[j] = -1;
      if (e < N_EDGES) {
        int d = dst[e];
        int s = src[e];
        pk[j] = ((unsigned)s << 5) | (unsigned)(d & 31);
        bk[j] = (short)(d >> 5);
        atomicAdd(&B.hcnt[d >> 5], 1);
      }
    }
    __syncthreads();

    // exclusive scan of hcnt[1563]: 7 counters/thread (256*7=1792 >= 1563)
    int c7[7];
    int s7 = 0;
    int base7 = t * 7;
#pragma unroll
    for (int j = 0; j < 7; ++j) {
      int idx = base7 + j;
      c7[j] = (idx < NBK) ? B.hcnt[idx] : 0;
      s7 += c7[j];
    }
    int incl = s7;
    int lane = t & 63, wid = t >> 6;
#pragma unroll
    for (int off = 1; off < 64; off <<= 1) {
      int n = __shfl_up(incl, off);
      if (lane >= off) incl += n;
    }
    if (lane == 63) B.wsums[wid] = incl;
    __syncthreads();
    int wbase = 0;
    for (int w2 = 0; w2 < wid; ++w2) wbase += B.wsums[w2];
    int run = wbase + incl - s7;
#pragma unroll
    for (int j = 0; j < 7; ++j) {
      int idx = base7 + j;
      if (idx < NBK) { B.hstart[idx] = run; B.hcur[idx] = run; }
      run += c7[j];
    }
    if (t == BIN_T - 1) B.tot = run;
    __syncthreads();

    // scatter into stage grouped by bucket (scalar LDS atomics only)
#pragma unroll
    for (int j = 0; j < 16; ++j) {
      if (bk[j] >= 0) {
        int p = atomicAdd(&B.hcur[bk[j]], 1);
        B.stage[p] = pk[j];
      }
    }
    __syncthreads();

    // flush: fully coalesced copy of this block's segment (uint4 wide)
    int tot = B.tot;
    unsigned* dseg = ebuf + (size_t)blk * BIN_CHUNK;
    int tot4 = tot >> 2;
    uint4* d4 = (uint4*)dseg;
    const uint4* s4p = (const uint4*)B.stage;
    for (int i = t; i < tot4; i += BIN_T) d4[i] = s4p[i];
    for (int i = (tot & ~3) + t; i < tot; i += BIN_T) dseg[i] = B.stage[i];

    // publish per-bucket offsets (coalesced, no atomics)
    int* orow = offs + (size_t)blk * OFFS_W;
    for (int i = t; i < NBK; i += BIN_T) orow[i] = B.hstart[i];
    if (t == 0) orow[NBK] = tot;
  }
}

// ===========================================================================
// gather_sorted: block per 32-node bucket (1563 blocks = 6.1/CU for TLP).
// Stitch from 196 segments (1/thread), in-LDS counting sort by local dst,
// wave-per-node full-row register gather (proven form), shfl reduce, bias.
// ===========================================================================
__global__ __launch_bounds__(256) void gather_sorted(
    const unsigned short* __restrict__ y, const unsigned* __restrict__ ebuf,
    const int* __restrict__ offs, const float* __restrict__ bias,
    float* __restrict__ out) {
  __shared__ int cnts[32];
  __shared__ int curs[32];
  __shared__ int starts[33];
  __shared__ int sorted[SORT_CAP];
  __shared__ unsigned ec[SORT_CAP];
  __shared__ int wsum2[4];
  __shared__ int segtot;

  int b = blockIdx.x;
  int t = threadIdx.x;
  if (t < 32) cnts[t] = 0;

  // ---- phase A: segment lengths (196 segs, 1 per thread) + block scan ----
  int s0 = 0, slen = 0;
  if (t < BIN_BLOCKS) {
    const int* orow = offs + (size_t)t * OFFS_W;
    s0 = orow[b];
    slen = orow[b + 1] - s0;
  }
  int lane = t & 63, wid = t >> 6;
  int v = slen;
#pragma unroll
  for (int off = 1; off < 64; off <<= 1) {
    int n = __shfl_up(v, off);
    if (lane >= off) v += n;
  }
  if (lane == 63) wsum2[wid] = v;
  __syncthreads();
  int wbase = 0;
  for (int w2 = 0; w2 < wid; ++w2) wbase += wsum2[w2];
  int base = wbase + v - slen;
  if (t == 255) segtot = wbase + v;

  // ---- phase B: copy my segment into the compact LDS edge list ----
  const unsigned* myseg = ebuf + (size_t)t * BIN_CHUNK + s0;
  for (int j = 0; j < slen; ++j) {
    int p = base + j;
    if (p < SORT_CAP) ec[p] = myseg[j];
  }
  __syncthreads();

  int cnt = segtot;
  if (cnt > SORT_CAP) cnt = SORT_CAP;

  // ---- counting sort by local dst (LDS only) ----
  for (int i = t; i < cnt; i += 256) atomicAdd(&cnts[ec[i] & 31u], 1);
  __syncthreads();

  if (t < 32) {
    int c = cnts[t];
    int vv = c;
#pragma unroll
    for (int off = 1; off < 32; off <<= 1) {
      int n = __shfl_up(vv, off);
      if (t >= off) vv += n;
    }
    starts[t] = vv - c;
    curs[t] = vv - c;
    if (t == 31) starts[32] = vv;
  }
  __syncthreads();

  for (int i = t; i < cnt; i += 256) {
    unsigned u = ec[i];
    int p = atomicAdd(&curs[u & 31u], 1);
    sorted[p] = (int)(u >> 5);
  }
  __syncthreads();

  // ---- wave-per-node register gather (full 256B rows) ----
  int wv = t >> 6;
  int g = lane >> 4;   // edge subgroup 0..3
  int l = lane & 15;   // 8-col chunk within row
  float4 bv0 = *(const float4*)(bias + l * 8);
  float4 bv1 = *(const float4*)(bias + l * 8 + 4);
  for (int n = wv; n < 32; n += 4) {
    int node = b * 32 + n;
    int beg = starts[n];
    int end = starts[n + 1];
    float acc[8] = {0.f, 0.f, 0.f, 0.f, 0.f, 0.f, 0.f, 0.f};
    int i = beg + g;
    for (; i + 12 < end; i += 16) {
      int s0e = sorted[i];
      int s1e = sorted[i + 4];
      int s2e = sorted[i + 8];
      int s3e = sorted[i + 12];
      uint4 u0 = *(const uint4*)(y + (size_t)s0e * D + l * 8);
      uint4 u1 = *(const uint4*)(y + (size_t)s1e * D + l * 8);
      uint4 u2 = *(const uint4*)(y + (size_t)s2e * D + l * 8);
      uint4 u3 = *(const uint4*)(y + (size_t)s3e * D + l * 8);
      acc[0] += (bf2f_lo(u0.x) + bf2f_lo(u1.x)) + (bf2f_lo(u2.x) + bf2f_lo(u3.x));
      acc[1] += (bf2f_hi(u0.x) + bf2f_hi(u1.x)) + (bf2f_hi(u2.x) + bf2f_hi(u3.x));
      acc[2] += (bf2f_lo(u0.y) + bf2f_lo(u1.y)) + (bf2f_lo(u2.y) + bf2f_lo(u3.y));
      acc[3] += (bf2f_hi(u0.y) + bf2f_hi(u1.y)) + (bf2f_hi(u2.y) + bf2f_hi(u3.y));
      acc[4] += (bf2f_lo(u0.z) + bf2f_lo(u1.z)) + (bf2f_lo(u2.z) + bf2f_lo(u3.z));
      acc[5] += (bf2f_hi(u0.z) + bf2f_hi(u1.z)) + (bf2f_hi(u2.z) + bf2f_hi(u3.z));
      acc[6] += (bf2f_lo(u0.w) + bf2f_lo(u1.w)) + (bf2f_lo(u2.w) + bf2f_lo(u3.w));
      acc[7] += (bf2f_hi(u0.w) + bf2f_hi(u1.w)) + (bf2f_hi(u2.w) + bf2f_hi(u3.w));
    }
    for (; i < end; i += 4) {
      int s = sorted[i];
      uint4 u = *(const uint4*)(y + (size_t)s * D + l * 8);
      acc[0] += bf2f_lo(u.x); acc[1] += bf2f_hi(u.x);
      acc[2] += bf2f_lo(u.y); acc[3] += bf2f_hi(u.y);
      acc[4] += bf2f_lo(u.z); acc[5] += bf2f_hi(u.z);
      acc[6] += bf2f_lo(u.w); acc[7] += bf2f_hi(u.w);
    }
#pragma unroll
    for (int j = 0; j < 8; ++j) {
      acc[j] += __shfl_xor(acc[j], 16);
      acc[j] += __shfl_xor(acc[j], 32);
    }
    if (g == 0 && node < N_NODES) {
      float4 r0 = {acc[0] + bv0.x, acc[1] + bv0.y, acc[2] + bv0.z, acc[3] + bv0.w};
      float4 r1 = {acc[4] + bv1.x, acc[5] + bv1.y, acc[6] + bv1.z, acc[7] + bv1.w};
      float* op = out + (size_t)node * D + l * 8;
      *(float4*)op = r0;
      *(float4*)(op + 4) = r1;
    }
  }
}

// ===========================================================================
// Fallback tier 1: CSR path (R5)
// ===========================================================================
__global__ __launch_bounds__(256) void hist_kernel(
    const int* __restrict__ dst, int* __restrict__ counts) {
  int e = blockIdx.x * 256 + threadIdx.x;
  if (e < N_EDGES) atomicAdd(&counts[dst[e]], 1);
}

#define SBLK 196
__global__ __launch_bounds__(256) void reduce_kernel(
    const int* __restrict__ counts, int* __restrict__ blockSums) {
  int i = blockIdx.x * 256 + threadIdx.x;
  int v = (i < N_NODES) ? counts[i] : 0;
#pragma unroll
  for (int off = 32; off; off >>= 1) v += __shfl_down(v, off);
  __shared__ int ws[4];
  int lane = threadIdx.x & 63, wid = threadIdx.x >> 6;
  if (lane == 0) ws[wid] = v;
  __syncthreads();
  if (threadIdx.x == 0) blockSums[blockIdx.x] = ws[0] + ws[1] + ws[2] + ws[3];
}

__global__ __launch_bounds__(256) void scan_kernel2(
    const int* __restrict__ counts, const int* __restrict__ blockSums,
    int* __restrict__ offsets, int* __restrict__ cursor) {
  int b = blockIdx.x;
  int t = threadIdx.x;
  int lane = t & 63, wid = t >> 6;
  int pv = (t < b) ? blockSums[t] : 0;
#pragma unroll
  for (int off = 32; off; off >>= 1) pv += __shfl_down(pv, off);
  __shared__ int ws[4];
  __shared__ int wsum[4];
  __shared__ int base_s;
  if (lane == 0) ws[wid] = pv;
  __syncthreads();
  if (t == 0) base_s = ws[0] + ws[1] + ws[2] + ws[3];
  int i = b * 256 + t;
  int c = (i < N_NODES) ? counts[i] : 0;
  int v = c;
#pragma unroll
  for (int off = 1; off < 64; off <<= 1) {
    int n = __shfl_up(v, off);
    if (lane >= off) v += n;
  }
  if (lane == 63) wsum[wid] = v;
  __syncthreads();
  int wbase = 0;
  for (int w2 = 0; w2 < wid; ++w2) wbase += wsum[w2];
  int excl = base_s + wbase + v - c;
  if (i < N_NODES) {
    offsets[i] = excl;
    cursor[i] = excl;
    if (i == N_NODES - 1) offsets[N_NODES] = excl + c;
  }
}

__global__ __launch_bounds__(256) void fill_kernel(
    const int* __restrict__ src, const int* __restrict__ dst,
    int* __restrict__ cursor, int* __restrict__ esrc) {
  int e = blockIdx.x * 256 + threadIdx.x;
  if (e >= N_EDGES) return;
  int pos = atomicAdd(&cursor[dst[e]], 1);
  esrc[pos] = src[e];
}

__global__ __launch_bounds__(256) void gemm_xw(
    const float* __restrict__ x, const float* __restrict__ W,
    unsigned short* __restrict__ y) {
  __shared__ unsigned short As[64 * LDA];
  __shared__ unsigned short Ws[128 * LDA];
  int t = threadIdx.x;
  int row0 = blockIdx.x * 64;
  for (int i = t; i < 2048; i += 256) {
    int r = i >> 5;
    int c4 = (i & 31) * 4;
    int gr = row0 + r;
    float4 v = (gr < N_NODES) ? *(const float4*)(x + (size_t)gr * D + c4)
                              : float4{0.f, 0.f, 0.f, 0.f};
    *(uint2*)&As[r * LDA + c4] = pack4bf(v);
  }
  for (int i = t; i < 4096; i += 256) {
    int r = i >> 5;
    int c4 = (i & 31) * 4;
    float4 wv = *(const float4*)(W + (size_t)r * D + c4);
    *(uint2*)&Ws[r * LDA + c4] = pack4bf(wv);
  }
  __syncthreads();
  int w = t >> 6;
  int lane = t & 63;
  int ln = lane & 15;
  int quad = lane >> 4;
  floatx4 acc[8];
#pragma unroll
  for (int n = 0; n < 8; ++n) acc[n] = floatx4{0.f, 0.f, 0.f, 0.f};
#pragma unroll
  for (int ks = 0; ks < 4; ++ks) {
    int kc = ks * 32 + quad * 8;
    bf16x8 a = *(const bf16x8*)&As[(w * 16 + ln) * LDA + kc];
#pragma unroll
    for (int n = 0; n < 8; ++n) {
      bf16x8 bf = *(const bf16x8*)&Ws[(n * 16 + ln) * LDA + kc];
      acc[n] = __builtin_amdgcn_mfma_f32_16x16x32_bf16(a, bf, acc[n], 0, 0, 0);
    }
  }
  int gr0 = row0 + w * 16 + quad * 4;
#pragma unroll
  for (int n = 0; n < 8; ++n) {
    int gc = n * 16 + ln;
#pragma unroll
    for (int r = 0; r < 4; ++r) {
      int gr = gr0 + r;
      if (gr < N_NODES) y[(size_t)gr * D + gc] = f2bf(acc[n][r]);
    }
  }
}

__global__ __launch_bounds__(256) void gather_ybf_kernel(
    const unsigned short* __restrict__ y, const int* __restrict__ esrc,
    const int* __restrict__ offsets, const float* __restrict__ bias,
    float* __restrict__ out) {
  int node = blockIdx.x * 4 + (threadIdx.x >> 6);
  if (node >= N_NODES) return;
  int lane = threadIdx.x & 63;
  int g = lane >> 4;
  int l = lane & 15;
  int beg = offsets[node];
  int end = offsets[node + 1];
  float acc[8] = {0.f, 0.f, 0.f, 0.f, 0.f, 0.f, 0.f, 0.f};
  int i = beg + g;
  for (; i + 4 < end; i += 8) {
    int s0 = esrc[i];
    int s1 = esrc[i + 4];
    uint4 u0 = *(const uint4*)(y + (size_t)s0 * D + l * 8);
    uint4 u1 = *(const uint4*)(y + (size_t)s1 * D + l * 8);
    acc[0] += bf2f_lo(u0.x) + bf2f_lo(u1.x);
    acc[1] += bf2f_hi(u0.x) + bf2f_hi(u1.x);
    acc[2] += bf2f_lo(u0.y) + bf2f_lo(u1.y);
    acc[3] += bf2f_hi(u0.y) + bf2f_hi(u1.y);
    acc[4] += bf2f_lo(u0.z) + bf2f_lo(u1.z);
    acc[5] += bf2f_hi(u0.z) + bf2f_hi(u1.z);
    acc[6] += bf2f_lo(u0.w) + bf2f_lo(u1.w);
    acc[7] += bf2f_hi(u0.w) + bf2f_hi(u1.w);
  }
  if (i < end) {
    int s = esrc[i];
    uint4 u = *(const uint4*)(y + (size_t)s * D + l * 8);
    acc[0] += bf2f_lo(u.x); acc[1] += bf2f_hi(u.x);
    acc[2] += bf2f_lo(u.y); acc[3] += bf2f_hi(u.y);
    acc[4] += bf2f_lo(u.z); acc[5] += bf2f_hi(u.z);
    acc[6] += bf2f_lo(u.w); acc[7] += bf2f_hi(u.w);
  }
#pragma unroll
  for (int j = 0; j < 8; ++j) {
    acc[j] += __shfl_xor(acc[j], 16);
    acc[j] += __shfl_xor(acc[j], 32);
  }
  if (g == 0) {
    const float* bp = bias + l * 8;
    float4 r0 = {acc[0] + bp[0], acc[1] + bp[1], acc[2] + bp[2], acc[3] + bp[3]};
    float4 r1 = {acc[4] + bp[4], acc[5] + bp[5], acc[6] + bp[6], acc[7] + bp[7]};
    float* op = out + (size_t)node * D + l * 8;
    *(float4*)op = r0;
    *(float4*)(op + 4) = r1;
  }
}

// ===========================================================================
// Fallback tier 2: atomic scatter + f32 transform.
// ===========================================================================
__global__ __launch_bounds__(256) void scatter_kernel(
    const float* __restrict__ x, const int* __restrict__ src,
    const int* __restrict__ dst, float* __restrict__ out) {
  int gtid = blockIdx.x * 256 + threadIdx.x;
  int e = gtid >> 6;
  int lane = threadIdx.x & 63;
  if (e >= N_EDGES) return;
  float2 v = ((const float2*)(x + (size_t)src[e] * D))[lane];
  float* orow = out + (size_t)dst[e] * D + lane * 2;
  atomicAdd(orow + 0, v.x);
  atomicAdd(orow + 1, v.y);
}

__global__ __launch_bounds__(256) void transform_kernel(
    float* __restrict__ out, const float* __restrict__ W,
    const float* __restrict__ bias) {
  constexpr int RPB = 64;
  constexpr int HP = 132;
  __shared__ float Hs[RPB][HP];
  int t = threadIdx.x;
  int row0 = blockIdx.x * RPB;
  int nr = min(RPB, N_NODES - row0);
  {
    const float4* g = (const float4*)(out + (size_t)row0 * D);
    for (int i = t; i < nr * (D / 4); i += 256) {
      int r = i >> 5;
      int c = (i & 31) * 4;
      *(float4*)&Hs[r][c] = g[i];
    }
  }
  __syncthreads();
  int tx = t & 15;
  int ty = t >> 4;
  int r0 = ty * 4;
  for (int half = 0; half < 2; ++half) {
    int oc0 = half * 64 + tx * 4;
    const float* Wb = W + (size_t)oc0 * D;
    float4 a0 = {0.f, 0.f, 0.f, 0.f}, a1 = {0.f, 0.f, 0.f, 0.f};
    float4 a2 = {0.f, 0.f, 0.f, 0.f}, a3 = {0.f, 0.f, 0.f, 0.f};
#pragma unroll 8
    for (int k = 0; k < D; k += 4) {
      float4 w0 = *(const float4*)(Wb + 0 * D + k);
      float4 w1 = *(const float4*)(Wb + 1 * D + k);
      float4 w2 = *(const float4*)(Wb + 2 * D + k);
      float4 w3 = *(const float4*)(Wb + 3 * D + k);
      float4 h0 = *(const float4*)&Hs[r0 + 0][k];
      float4 h1 = *(const float4*)&Hs[r0 + 1][k];
      float4 h2 = *(const float4*)&Hs[r0 + 2][k];
      float4 h3 = *(const float4*)&Hs[r0 + 3][k];
#define DOT(hv, wv) fmaf((hv).w, (wv).w, fmaf((hv).z, (wv).z, fmaf((hv).y, (wv).y, (hv).x * (wv).x)))
      a0.x += DOT(h0, w0); a0.y += DOT(h0, w1); a0.z += DOT(h0, w2); a0.w += DOT(h0, w3);
      a1.x += DOT(h1, w0); a1.y += DOT(h1, w1); a1.z += DOT(h1, w2); a1.w += DOT(h1, w3);
      a2.x += DOT(h2, w0); a2.y += DOT(h2, w1); a2.z += DOT(h2, w2); a2.w += DOT(h2, w3);
      a3.x += DOT(h3, w0); a3.y += DOT(h3, w1); a3.z += DOT(h3, w2); a3.w += DOT(h3, w3);
#undef DOT
    }
    float4 bv = *(const float4*)(bias + oc0);
    a0.x += bv.x; a0.y += bv.y; a0.z += bv.z; a0.w += bv.w;
    a1.x += bv.x; a1.y += bv.y; a1.z += bv.z; a1.w += bv.w;
    a2.x += bv.x; a2.y += bv.y; a2.z += bv.z; a2.w += bv.w;
    a3.x += bv.x; a3.y += bv.y; a3.z += bv.z; a3.w += bv.w;
    if (r0 + 0 < nr) *(float4*)(out + (size_t)(row0 + r0 + 0) * D + oc0) = a0;
    if (r0 + 1 < nr) *(float4*)(out + (size_t)(row0 + r0 + 1) * D + oc0) = a1;
    if (r0 + 2 < nr) *(float4*)(out + (size_t)(row0 + r0 + 2) * D + oc0) = a2;
    if (r0 + 3 < nr) *(float4*)(out + (size_t)(row0 + r0 + 3) * D + oc0) = a3;
  }
}

extern "C" void kernel_launch(void* const* d_in, const int* in_sizes, int n_in,
                              void* d_out, int out_size, void* d_ws, size_t ws_size,
                              hipStream_t stream) {
  const float* x = (const float*)d_in[0];
  const int* src = (const int*)d_in[1];
  const int* dst = (const int*)d_in[2];
  const float* W = (const float*)d_in[3];
  const float* b = (const float*)d_in[4];
  float* out = (float*)d_out;

  const size_t ybytes = (size_t)N_NODES * D * sizeof(unsigned short);      // 12.8 MB
  const size_t ebytes = (size_t)BIN_BLOCKS * BIN_CHUNK * sizeof(unsigned); // 3.2 MB
  const size_t obytes = (size_t)BIN_BLOCKS * OFFS_W * sizeof(int);         // 1.2 MB
  const size_t wbytes = (size_t)D * D * sizeof(unsigned short);            // 32 KB

  if (ws_size >= ybytes + ebytes + obytes + wbytes) {
    unsigned short* y = (unsigned short*)d_ws;
    unsigned* ebuf = (unsigned*)((char*)d_ws + ybytes);
    int* offs = (int*)((char*)ebuf + ebytes);
    unsigned short* wbf = (unsigned short*)((char*)offs + obytes);

    wconv_kernel<<<16, 256, 0, stream>>>(W, wbf);
    prep_kernel<<<BIN_BLOCKS + NB, 256, 0, stream>>>(x, wbf, y, src, dst, ebuf, offs);
    gather_sorted<<<NBK, 256, 0, stream>>>(y, ebuf, offs, b, out);
    return;
  }

  const size_t A = 50048;
  const size_t head_ints = 3 * A + 256 + (size_t)N_EDGES;
  const size_t need_csr = head_ints * sizeof(int) + ybytes;

  if (ws_size >= need_csr) {
    int* counts     = (int*)d_ws;
    int* offsets    = counts + A;
    int* cursor     = offsets + A;
    int* blockSums  = cursor + A;
    int* esrc       = blockSums + 256;
    unsigned short* y = (unsigned short*)(esrc + N_EDGES);

    hipMemsetAsync(counts, 0, N_NODES * sizeof(int), stream);
    hist_kernel<<<(N_EDGES + 255) / 256, 256, 0, stream>>>(dst, counts);
    reduce_kernel<<<SBLK, 256, 0, stream>>>(counts, blockSums);
    scan_kernel2<<<SBLK, 256, 0, stream>>>(counts, blockSums, offsets, cursor);
    fill_kernel<<<(N_EDGES + 255) / 256, 256, 0, stream>>>(src, dst, cursor, esrc);
    gemm_xw<<<NB, 256, 0, stream>>>(x, W, y);
    gather_ybf_kernel<<<(N_NODES + 3) / 4, 256, 0, stream>>>(y, esrc, offsets, b, out);
  } else {
    hipMemsetAsync(out, 0, (size_t)N_NODES * D * sizeof(float), stream);
    scatter_kernel<<<N_EDGES / 4, 256, 0, stream>>>(x, src, dst, out);
    transform_kernel<<<(N_NODES + 63) / 64, 256, 0, stream>>>(out, W, b);
  }
}